// Round 1
// baseline (400.912 us; speedup 1.0000x reference)
//
#include <hip/hip_runtime.h>

// Problem constants (match reference):
#define BB   256      // batch
#define LL   2048     // sequence length
#define DD   128      // embedding dim
#define TMAX 48       // number of time bins
#define BLOCK 1024    // 16 waves
#define NWAVE (BLOCK / 64)
#define TOK_PER_WAVE (LL / NWAVE)   // 128

// One block per batch row b. LDS holds the full [48][128] fp32 accumulator
// (24 KB), per-token staged metadata (16 KB), and bin counts.
// Accumulation uses LDS float atomics (ds_add_f32, fire-and-forget): no
// register RMW dependency chain, tokens fully pipelined.
__global__ __launch_bounds__(BLOCK, 1) void embed_bin_kernel(
    const float* __restrict__ X,      // [B][L][2]  (T, id-as-float)
    const float* __restrict__ embX,   // [V][D]
    const float* __restrict__ embW,   // [V+1]
    float* __restrict__ out)          // [B][TMAX][D]
{
    __shared__ float  s_acc[TMAX * DD];   // 24 KB segment sums
    __shared__ float2 s_mw[LL];           // 16 KB: .x = bitcast(id | bin<<16), .y = exp(embW[id])
    __shared__ int    s_cnt[TMAX];

    const int b    = blockIdx.x;
    const int tid  = threadIdx.x;
    const int lane = tid & 63;
    const int wv   = tid >> 6;

    // ---- init accumulators (d_out/d_ws are poisoned; LDS is ours to zero) ----
    for (int i = tid; i < TMAX * DD; i += BLOCK) s_acc[i] = 0.0f;
    if (tid < TMAX) s_cnt[tid] = 0;
    __syncthreads();

    // ---- phase 1: stage per-token metadata, histogram counts ----
    const float2* Xb = (const float2*)(X + (size_t)b * LL * 2);
    for (int l = tid; l < LL; l += BLOCK) {
        float2 x = Xb[l];                 // coalesced 8B loads
        int id  = (int)x.y;               // ids in [1, V), exact in fp32
        int bin = (int)x.x;               // T >= 0, trunc == floor
        bin = bin < 0 ? 0 : (bin > TMAX - 1 ? TMAX - 1 : bin);
        float w = __expf(embW[id]);       // embW fits in L1/L2
        float2 mw;
        mw.x = __int_as_float(id | (bin << 16));
        mw.y = w;
        s_mw[l] = mw;
        atomicAdd(&s_cnt[bin], 1);        // ds_add_u32, 2048 ops total — cheap
    }
    __syncthreads();

    // ---- phase 2: gather + weighted accumulate into LDS ----
    // Wave wv owns tokens [wv*128, wv*128+128). 64 lanes cover D=128 as float2.
    const int col  = lane << 1;
    const int base = wv * TOK_PER_WAVE;
    for (int l = base; l < base + TOK_PER_WAVE; l += 8) {
        float2 e[8];
        float  wt[8];
        int    off[8];
        // issue 8 independent gathers (L2-resident embX rows) before consuming
        #pragma unroll
        for (int j = 0; j < 8; ++j) {
            float2 mw = s_mw[l + j];              // LDS broadcast read
            int m  = __float_as_int(mw.x);
            int id = m & 0xFFFF;
            off[j] = (m >> 16) * DD + col;        // bin*D + col
            wt[j]  = mw.y;
            e[j]   = *(const float2*)(embX + id * DD + col);
        }
        #pragma unroll
        for (int j = 0; j < 8; ++j) {
            // fire-and-forget LDS float atomics: no RMW register chain.
            atomicAdd(&s_acc[off[j]],     wt[j] * e[j].x);
            atomicAdd(&s_acc[off[j] + 1], wt[j] * e[j].y);
        }
    }
    __syncthreads();

    // ---- phase 3: divide by counts, coalesced store ----
    float* outb = out + (size_t)b * TMAX * DD;
    for (int i = tid; i < TMAX * DD; i += BLOCK) {
        float c = (float)s_cnt[i >> 7];           // i / DD
        outb[i] = s_acc[i] / (c + 1e-6f);
    }
}

extern "C" void kernel_launch(void* const* d_in, const int* in_sizes, int n_in,
                              void* d_out, int out_size, void* d_ws, size_t ws_size,
                              hipStream_t stream) {
    const float* X    = (const float*)d_in[0];   // B*L*2 fp32
    const float* embX = (const float*)d_in[1];   // V*D fp32
    const float* embW = (const float*)d_in[2];   // (V+1) fp32
    float* out        = (float*)d_out;           // B*TMAX*D fp32

    embed_bin_kernel<<<dim3(BB), dim3(BLOCK), 0, stream>>>(X, embX, embW, out);
}

// Round 2
// 80.542 us; speedup vs baseline: 4.9777x; 4.9777x over previous
//
#include <hip/hip_runtime.h>

// Problem constants (match reference):
#define BB   256      // batch
#define LL   2048     // sequence length
#define DD   128      // embedding dim
#define TMAX 48       // time bins
#define BLOCK 1024    // 16 waves
#define NWAVE (BLOCK / 64)

// One block per batch row b.
// R1 lesson: shared-float atomicAdd lowers to a CAS loop (345us, all pipes
// idle). This version has ZERO float atomics: counting-sort tokens by bin
// in LDS (native int atomics only), then each bin is owned by exactly one
// wave which accumulates in registers and writes its output row directly.
__global__ __launch_bounds__(BLOCK, 1) void embed_bin_kernel(
    const float* __restrict__ X,      // [B][L][2]  (T, id-as-float)
    const float* __restrict__ embX,   // [V][D]
    const float* __restrict__ embW,   // [V+1]
    float* __restrict__ out)          // [B][TMAX][D]
{
    __shared__ float2 s_meta[LL];     // 16 KB: .x = bits(id | bin<<16), .y = w
    __shared__ float2 s_sorted[LL];   // 16 KB: bin-sorted (.x = bits(id), .y = w)
    __shared__ int    s_cnt[TMAX];
    __shared__ int    s_start[TMAX];
    __shared__ int    s_ofs[TMAX];

    const int b    = blockIdx.x;
    const int tid  = threadIdx.x;
    const int lane = tid & 63;
    const int wv   = tid >> 6;

    if (tid < TMAX) s_cnt[tid] = 0;
    __syncthreads();

    // ---- phase 1: stage per-token metadata + int histogram (native ds_add) ----
    const float2* Xb = (const float2*)(X + (size_t)b * LL * 2);
    for (int l = tid; l < LL; l += BLOCK) {
        float2 x = Xb[l];                 // coalesced 8B loads
        int id  = (int)x.y;               // ids in [1, V), exact in fp32
        int bin = (int)x.x;               // T >= 0, trunc == floor
        bin = bin < 0 ? 0 : (bin > TMAX - 1 ? TMAX - 1 : bin);
        float w = __expf(embW[id]);       // embW (24 KB) is L1-resident
        float2 m;
        m.x = __int_as_float(id | (bin << 16));
        m.y = w;
        s_meta[l] = m;
        atomicAdd(&s_cnt[bin], 1);        // native ds_add_u32
    }
    __syncthreads();

    // ---- prefix sum over 48 bins (wave 0, shfl scan) ----
    if (wv == 0) {
        int orig = (lane < TMAX) ? s_cnt[lane] : 0;
        int c = orig;
        #pragma unroll
        for (int d = 1; d < 64; d <<= 1) {
            int t = __shfl_up(c, d);
            if (lane >= d) c += t;
        }
        if (lane < TMAX) { s_start[lane] = c - orig; s_ofs[lane] = c - orig; }
    }
    __syncthreads();

    // ---- counting-sort scatter (native int atomics, 2048 total) ----
    for (int l = tid; l < LL; l += BLOCK) {
        float2 m = s_meta[l];
        int bits = __float_as_int(m.x);
        int bin  = bits >> 16;
        int pos  = atomicAdd(&s_ofs[bin], 1);   // ds_add_rtn_u32
        float2 sm;
        sm.x = __int_as_float(bits & 0xFFFF);
        sm.y = m.y;
        s_sorted[pos] = sm;                     // scattered ds_write_b64
    }
    __syncthreads();

    // ---- phase 2: one wave per bin, register accumulation, no atomics ----
    const int col = lane << 1;                  // 64 lanes x float2 = D=128
    for (int t = wv; t < TMAX; t += NWAVE) {    // 3 bins per wave
        const int start = s_start[t];
        const int n     = s_cnt[t];
        float2 a0 = {0.f, 0.f}, a1 = {0.f, 0.f}, a2 = {0.f, 0.f}, a3 = {0.f, 0.f};
        int i = 0;
        for (; i + 4 <= n; i += 4) {            // 4 gathers in flight per wave
            float2 m0 = s_sorted[start + i];
            float2 m1 = s_sorted[start + i + 1];
            float2 m2 = s_sorted[start + i + 2];
            float2 m3 = s_sorted[start + i + 3];
            float2 e0 = *(const float2*)(embX + __float_as_int(m0.x) * DD + col);
            float2 e1 = *(const float2*)(embX + __float_as_int(m1.x) * DD + col);
            float2 e2 = *(const float2*)(embX + __float_as_int(m2.x) * DD + col);
            float2 e3 = *(const float2*)(embX + __float_as_int(m3.x) * DD + col);
            a0.x = fmaf(m0.y, e0.x, a0.x); a0.y = fmaf(m0.y, e0.y, a0.y);
            a1.x = fmaf(m1.y, e1.x, a1.x); a1.y = fmaf(m1.y, e1.y, a1.y);
            a2.x = fmaf(m2.y, e2.x, a2.x); a2.y = fmaf(m2.y, e2.y, a2.y);
            a3.x = fmaf(m3.y, e3.x, a3.x); a3.y = fmaf(m3.y, e3.y, a3.y);
        }
        for (; i < n; ++i) {                    // tail
            float2 m0 = s_sorted[start + i];
            float2 e0 = *(const float2*)(embX + __float_as_int(m0.x) * DD + col);
            a0.x = fmaf(m0.y, e0.x, a0.x); a0.y = fmaf(m0.y, e0.y, a0.y);
        }
        float sx = (a0.x + a1.x) + (a2.x + a3.x);
        float sy = (a0.y + a1.y) + (a2.y + a3.y);
        float c  = (float)n + 1e-6f;
        float2 r;
        r.x = sx / c;
        r.y = sy / c;
        // coalesced 512B store per wave, each bin written by exactly one wave
        *(float2*)(out + (size_t)b * TMAX * DD + t * DD + col) = r;
    }
}

extern "C" void kernel_launch(void* const* d_in, const int* in_sizes, int n_in,
                              void* d_out, int out_size, void* d_ws, size_t ws_size,
                              hipStream_t stream) {
    const float* X    = (const float*)d_in[0];   // B*L*2 fp32
    const float* embX = (const float*)d_in[1];   // V*D fp32
    const float* embW = (const float*)d_in[2];   // (V+1) fp32
    float* out        = (float*)d_out;           // B*TMAX*D fp32

    embed_bin_kernel<<<dim3(BB), dim3(BLOCK), 0, stream>>>(X, embX, embW, out);
}

// Round 3
// 75.018 us; speedup vs baseline: 5.3442x; 1.0736x over previous
//
#include <hip/hip_runtime.h>

// Problem constants (match reference):
#define BB   256      // batch
#define LL   2048     // sequence length
#define DD   128      // embedding dim
#define TMAX 48       // time bins
#define BLOCK 1024    // 16 waves
#define NWAVE (BLOCK / 64)
#define TPT  (LL / BLOCK)   // tokens per thread = 2

// One block per batch row b.
// R1: shared-float atomicAdd = CAS loop (345us) -> counting-sort + register acc (80us).
// R3: float4 half-wave gathers (16B/lane), token pairing (2 tokens per wave-load
// step), metadata in registers (no s_meta), 8 tokens in flight per wave.
__global__ __launch_bounds__(BLOCK, 1) void embed_bin_kernel(
    const float* __restrict__ X,      // [B][L][2]  (T, id-as-float)
    const float* __restrict__ embX,   // [V][D]
    const float* __restrict__ embW,   // [V+1]
    float* __restrict__ out)          // [B][TMAX][D]
{
    __shared__ float2 s_sorted[LL];   // 16 KB: bin-sorted (.x = bits(id), .y = w)
    __shared__ int    s_cnt[TMAX];
    __shared__ int    s_start[TMAX];
    __shared__ int    s_ofs[TMAX];

    const int b    = blockIdx.x;
    const int tid  = threadIdx.x;
    const int lane = tid & 63;
    const int wv   = tid >> 6;

    if (tid < TMAX) s_cnt[tid] = 0;
    __syncthreads();

    // ---- phase 1: parse 2 tokens/thread into REGISTERS + int histogram ----
    const float2* Xb = (const float2*)(X + (size_t)b * LL * 2);
    int   tok_bits[TPT];   // id | bin<<16
    float tok_w[TPT];
    #pragma unroll
    for (int j = 0; j < TPT; ++j) {
        float2 x = Xb[tid + j * BLOCK];   // coalesced 8B loads
        int id  = (int)x.y;               // ids in [1, V), exact in fp32
        int bin = (int)x.x;               // T >= 0, trunc == floor
        bin = bin < 0 ? 0 : (bin > TMAX - 1 ? TMAX - 1 : bin);
        tok_bits[j] = id | (bin << 16);
        tok_w[j]    = __expf(embW[id]);   // embW (24 KB) is L1/L2-resident
        atomicAdd(&s_cnt[bin], 1);        // native ds_add_u32
    }
    __syncthreads();

    // ---- prefix sum over 48 bins (wave 0, shfl scan) ----
    if (wv == 0) {
        int orig = (lane < TMAX) ? s_cnt[lane] : 0;
        int c = orig;
        #pragma unroll
        for (int d = 1; d < 64; d <<= 1) {
            int t = __shfl_up(c, d);
            if (lane >= d) c += t;
        }
        if (lane < TMAX) { s_start[lane] = c - orig; s_ofs[lane] = c - orig; }
    }
    __syncthreads();

    // ---- counting-sort scatter straight from registers ----
    #pragma unroll
    for (int j = 0; j < TPT; ++j) {
        int bin = tok_bits[j] >> 16;
        int pos = atomicAdd(&s_ofs[bin], 1);    // ds_add_rtn_u32
        float2 sm;
        sm.x = __int_as_float(tok_bits[j] & 0xFFFF);
        sm.y = tok_w[j];
        s_sorted[pos] = sm;                     // scattered ds_write_b64
    }
    __syncthreads();

    // ---- phase 2: one wave per bin; half-wave float4 gathers, 2 tokens/step ----
    const int half = lane >> 5;                 // which token of the pair
    const int col4 = (lane & 31) << 2;          // 32 lanes x float4 = D=128
    for (int t = wv; t < TMAX; t += NWAVE) {    // 3 bins per wave
        const int start = s_start[t];
        const int n     = s_cnt[t];
        float4 a0 = {0,0,0,0}, a1 = {0,0,0,0}, a2 = {0,0,0,0}, a3 = {0,0,0,0};
        for (int i = 0; i < n; i += 8) {        // 8 tokens (4 wave-loads) in flight
            float4 e[4];
            float  w[4];
            #pragma unroll
            for (int j = 0; j < 4; ++j) {
                int k = i + 2 * j + half;
                bool valid = k < n;
                float2 m = s_sorted[start + (valid ? k : 0)];  // n>0 here
                w[j] = valid ? m.y : 0.0f;
                e[j] = *(const float4*)(embX + __float_as_int(m.x) * DD + col4);
            }
            a0.x = fmaf(w[0], e[0].x, a0.x); a0.y = fmaf(w[0], e[0].y, a0.y);
            a0.z = fmaf(w[0], e[0].z, a0.z); a0.w = fmaf(w[0], e[0].w, a0.w);
            a1.x = fmaf(w[1], e[1].x, a1.x); a1.y = fmaf(w[1], e[1].y, a1.y);
            a1.z = fmaf(w[1], e[1].z, a1.z); a1.w = fmaf(w[1], e[1].w, a1.w);
            a2.x = fmaf(w[2], e[2].x, a2.x); a2.y = fmaf(w[2], e[2].y, a2.y);
            a2.z = fmaf(w[2], e[2].z, a2.z); a2.w = fmaf(w[2], e[2].w, a2.w);
            a3.x = fmaf(w[3], e[3].x, a3.x); a3.y = fmaf(w[3], e[3].y, a3.y);
            a3.z = fmaf(w[3], e[3].z, a3.z); a3.w = fmaf(w[3], e[3].w, a3.w);
        }
        float4 a;
        a.x = (a0.x + a1.x) + (a2.x + a3.x);
        a.y = (a0.y + a1.y) + (a2.y + a3.y);
        a.z = (a0.z + a1.z) + (a2.z + a3.z);
        a.w = (a0.w + a1.w) + (a2.w + a3.w);
        // combine the two token-halves (same columns, different tokens)
        a.x += __shfl_xor(a.x, 32);
        a.y += __shfl_xor(a.y, 32);
        a.z += __shfl_xor(a.z, 32);
        a.w += __shfl_xor(a.w, 32);
        if (half == 0) {
            float inv = 1.0f / ((float)n + 1e-6f);
            float4 r = { a.x * inv, a.y * inv, a.z * inv, a.w * inv };
            // 32 lanes x 16B = 512B coalesced store per bin row
            *(float4*)(out + (size_t)b * TMAX * DD + t * DD + col4) = r;
        }
    }
}

extern "C" void kernel_launch(void* const* d_in, const int* in_sizes, int n_in,
                              void* d_out, int out_size, void* d_ws, size_t ws_size,
                              hipStream_t stream) {
    const float* X    = (const float*)d_in[0];   // B*L*2 fp32
    const float* embX = (const float*)d_in[1];   // V*D fp32
    const float* embW = (const float*)d_in[2];   // (V+1) fp32
    float* out        = (float*)d_out;           // B*TMAX*D fp32

    embed_bin_kernel<<<dim3(BB), dim3(BLOCK), 0, stream>>>(X, embX, embW, out);
}